// Round 1
// baseline (413.175 us; speedup 1.0000x reference)
//
#include <hip/hip_runtime.h>

// Problem constants
#define L_SEQ 2048
#define DIM   1024
#define NH    16
#define HDIM  64
#define KDIM  1024   // K for both GEMMs

typedef short  short8 __attribute__((ext_vector_type(8)));
typedef __bf16 bf16x8 __attribute__((ext_vector_type(8)));
typedef float  f32x4  __attribute__((ext_vector_type(4)));

__device__ __forceinline__ unsigned short f2bf(float f) {
  unsigned u = __builtin_bit_cast(unsigned, f);
  u += 0x7fffu + ((u >> 16) & 1u);   // RNE
  return (unsigned short)(u >> 16);
}

__device__ __forceinline__ void gload16(const void* g, void* l) {
  __builtin_amdgcn_global_load_lds(
      (const __attribute__((address_space(1))) void*)g,
      (__attribute__((address_space(3))) void*)l, 16, 0, 0);
}

// ---------------- fp32 -> bf16 conversion ----------------
__global__ __launch_bounds__(256) void cvt_bf16(const float* __restrict__ src,
                                                unsigned short* __restrict__ dst,
                                                int n) {
  int i = (blockIdx.x * 256 + threadIdx.x) * 8;
  if (i >= n) return;
  f32x4 a = *(const f32x4*)(src + i);
  f32x4 b = *(const f32x4*)(src + i + 4);
  short8 o;
  o[0] = (short)f2bf(a[0]); o[1] = (short)f2bf(a[1]);
  o[2] = (short)f2bf(a[2]); o[3] = (short)f2bf(a[3]);
  o[4] = (short)f2bf(b[0]); o[5] = (short)f2bf(b[1]);
  o[6] = (short)f2bf(b[2]); o[7] = (short)f2bf(b[3]);
  *(short8*)(dst + i) = o;
}

// ---------------- 128x128 NT GEMM mainloop (m97 structure) ----------------
// A: [M,1024] row-major bf16; Bt: [N,1024] row-major bf16 (i.e. B transposed).
__device__ __forceinline__ void gemm128_mainloop(
    const unsigned short* __restrict__ A, const unsigned short* __restrict__ Bt,
    int m0, int n0, unsigned short* As, unsigned short* Bs, f32x4 (&acc)[4][4]) {
  const int t = threadIdx.x;
  const int wid = t >> 6, lane = t & 63;
  const int wm = wid >> 1, wn = wid & 1;
  const int lr = lane & 15, lk = (lane >> 4) * 8;
  for (int kt = 0; kt < KDIM / 64; ++kt) {
    __syncthreads();   // previous iteration's reads complete
#pragma unroll
    for (int i = 0; i < 4; ++i) {
      int c = i * 256 + t;               // 16B chunk id, row=c>>3
      int row = c >> 3, cc = (c & 7) * 8;
      gload16(A  + (size_t)(m0 + row) * KDIM + kt * 64 + cc, As + c * 8);
      gload16(Bt + (size_t)(n0 + row) * KDIM + kt * 64 + cc, Bs + c * 8);
    }
    asm volatile("s_waitcnt vmcnt(0)" ::: "memory");
    __syncthreads();   // all waves' loads visible
    bf16x8 af[4][2], bfv[4][2];
#pragma unroll
    for (int mf = 0; mf < 4; ++mf)
#pragma unroll
      for (int kh = 0; kh < 2; ++kh)
        af[mf][kh] = __builtin_bit_cast(bf16x8,
            *(const short8*)(As + (wm * 64 + mf * 16 + lr) * 64 + kh * 32 + lk));
#pragma unroll
    for (int nf = 0; nf < 4; ++nf)
#pragma unroll
      for (int kh = 0; kh < 2; ++kh)
        bfv[nf][kh] = __builtin_bit_cast(bf16x8,
            *(const short8*)(Bs + (wn * 64 + nf * 16 + lr) * 64 + kh * 32 + lk));
#pragma unroll
    for (int mf = 0; mf < 4; ++mf)
#pragma unroll
      for (int nf = 0; nf < 4; ++nf)
#pragma unroll
        for (int kh = 0; kh < 2; ++kh)
          acc[mf][nf] = __builtin_amdgcn_mfma_f32_16x16x32_bf16(
              af[mf][kh], bfv[nf][kh], acc[mf][nf], 0, 0, 0);
  }
}

// ---------------- GEMM1: qkv = x @ Wqkv^T, scatter into head layouts ----------------
__global__ __launch_bounds__(256) void gemm_qkv(
    const unsigned short* __restrict__ xb, const unsigned short* __restrict__ wb,
    unsigned short* __restrict__ qw, unsigned short* __restrict__ kw,
    unsigned short* __restrict__ vtw) {
  __shared__ unsigned short As[128 * 64], Bs[128 * 64];
  f32x4 acc[4][4] = {};
  const int n0 = blockIdx.x * 128, m0 = blockIdx.y * 128;
  gemm128_mainloop(xb, wb, m0, n0, As, Bs, acc);
  const int t = threadIdx.x, wid = t >> 6, lane = t & 63;
  const int wm = wid >> 1, wn = wid & 1;
#pragma unroll
  for (int mf = 0; mf < 4; ++mf)
#pragma unroll
    for (int nf = 0; nf < 4; ++nf) {
      int e = n0 + wn * 64 + nf * 16 + (lane & 15);
      int sec = e >> 10;                  // 0=Q 1=K 2=V (block-uniform)
      int h = (e & 1023) >> 6, hd = e & 63;
#pragma unroll
      for (int r = 0; r < 4; ++r) {
        int m = m0 + wm * 64 + mf * 16 + (lane >> 4) * 4 + r;
        int b = m >> 11, li = m & 2047;
        size_t bh = (size_t)(b * NH + h);
        unsigned short val = f2bf(acc[mf][nf][r]);
        if (sec == 0)      qw[(bh * L_SEQ + li) * HDIM + hd] = val;
        else if (sec == 1) kw[(bh * L_SEQ + li) * HDIM + hd] = val;
        else               vtw[(bh * HDIM + hd) * L_SEQ + li] = val;  // V^T
      }
    }
}

// ---------------- GEMM2: out = y @ Wproj^T (fp32 out) ----------------
__global__ __launch_bounds__(256) void gemm_proj(
    const unsigned short* __restrict__ yb, const unsigned short* __restrict__ wb,
    float* __restrict__ out) {
  __shared__ unsigned short As[128 * 64], Bs[128 * 64];
  f32x4 acc[4][4] = {};
  const int n0 = blockIdx.x * 128, m0 = blockIdx.y * 128;
  gemm128_mainloop(yb, wb, m0, n0, As, Bs, acc);
  const int t = threadIdx.x, wid = t >> 6, lane = t & 63;
  const int wm = wid >> 1, wn = wid & 1;
#pragma unroll
  for (int mf = 0; mf < 4; ++mf)
#pragma unroll
    for (int nf = 0; nf < 4; ++nf) {
      int e = n0 + wn * 64 + nf * 16 + (lane & 15);
#pragma unroll
      for (int r = 0; r < 4; ++r) {
        int m = m0 + wm * 64 + mf * 16 + (lane >> 4) * 4 + r;
        out[(size_t)m * DIM + e] = acc[mf][nf][r];
      }
    }
}

// ---------------- Flash attention with key-padding mask ----------------
// grid: (L/128, B*H). block 256 = 4 waves; each wave owns 32 query rows.
__global__ __launch_bounds__(256) void attn_kernel(
    const unsigned short* __restrict__ qw, const unsigned short* __restrict__ kw,
    const unsigned short* __restrict__ vtw, const int* __restrict__ mask,
    unsigned short* __restrict__ yb) {
  __shared__ unsigned short Ks[64 * 64];    // [kv][hd]
  __shared__ unsigned short Vts[64 * 64];   // [hd][kv]
  __shared__ unsigned short Ps[128 * 64];   // [q][kv], per-wave private rows
  const int bh = blockIdx.y;
  const int q0 = blockIdx.x * 128;
  const int b = bh >> 4, h = bh & 15;
  const int t = threadIdx.x, wid = t >> 6, lane = t & 63;
  const int lr = lane & 15, lk = (lane >> 4) * 8;
  const float KE = 0.18033688011112042f;    // (1/sqrt(64)) * log2(e)

  // Q fragments in registers (rows q0 + wid*32 .. +32)
  bf16x8 qf[2][2];
  const size_t qbase = (size_t)bh * L_SEQ + q0 + wid * 32;
#pragma unroll
  for (int mf = 0; mf < 2; ++mf)
#pragma unroll
    for (int kh = 0; kh < 2; ++kh)
      qf[mf][kh] = __builtin_bit_cast(bf16x8,
          *(const short8*)(qw + (qbase + mf * 16 + lr) * HDIM + kh * 32 + lk));

  f32x4 o[2][4] = {};
  float mrun[2][4], lrun[2][4];
#pragma unroll
  for (int mf = 0; mf < 2; ++mf)
#pragma unroll
    for (int r = 0; r < 4; ++r) { mrun[mf][r] = -3.0e38f; lrun[mf][r] = 0.f; }

  for (int kt = 0; kt < L_SEQ / 64; ++kt) {
    const int kv0 = kt * 64;
    __syncthreads();   // previous tile's LDS reads done
#pragma unroll
    for (int i = 0; i < 2; ++i) {
      int c = i * 256 + t;
      int row = c >> 3, cc = (c & 7) * 8;
      gload16(kw  + ((size_t)bh * L_SEQ + kv0 + row) * HDIM + cc, Ks  + c * 8);
      gload16(vtw + ((size_t)bh * HDIM + row) * L_SEQ + kv0 + cc, Vts + c * 8);
    }
    asm volatile("s_waitcnt vmcnt(0)" ::: "memory");
    __syncthreads();

    // mask flags for this lane's 4 key columns
    int mk[4];
#pragma unroll
    for (int nf = 0; nf < 4; ++nf)
      mk[nf] = mask[b * L_SEQ + kv0 + nf * 16 + lr];

    // QK^T
    bf16x8 kf[4][2];
#pragma unroll
    for (int nf = 0; nf < 4; ++nf)
#pragma unroll
      for (int kh = 0; kh < 2; ++kh)
        kf[nf][kh] = __builtin_bit_cast(bf16x8,
            *(const short8*)(Ks + (nf * 16 + lr) * 64 + kh * 32 + lk));
    f32x4 s[2][4] = {};
#pragma unroll
    for (int mf = 0; mf < 2; ++mf)
#pragma unroll
      for (int nf = 0; nf < 4; ++nf)
#pragma unroll
        for (int kh = 0; kh < 2; ++kh)
          s[mf][nf] = __builtin_amdgcn_mfma_f32_16x16x32_bf16(
              qf[mf][kh], kf[nf][kh], s[mf][nf], 0, 0, 0);

    // online softmax per mf
#pragma unroll
    for (int mf = 0; mf < 2; ++mf) {
      float mt[4];
#pragma unroll
      for (int r = 0; r < 4; ++r) {
        float v0 = mk[0] ? -3.0e38f : s[mf][0][r];
        float v1 = mk[1] ? -3.0e38f : s[mf][1][r];
        float v2 = mk[2] ? -3.0e38f : s[mf][2][r];
        float v3 = mk[3] ? -3.0e38f : s[mf][3][r];
        mt[r] = fmaxf(fmaxf(v0, v1), fmaxf(v2, v3));
      }
#pragma unroll
      for (int xm = 1; xm < 16; xm <<= 1)
#pragma unroll
        for (int r = 0; r < 4; ++r)
          mt[r] = fmaxf(mt[r], __shfl_xor(mt[r], xm));
      float al[4];
#pragma unroll
      for (int r = 0; r < 4; ++r) {
        float mn = fmaxf(mrun[mf][r], mt[r]);
        al[r] = __builtin_amdgcn_exp2f((mrun[mf][r] - mn) * KE);
        mrun[mf][r] = mn;
      }
      float rs[4] = {0.f, 0.f, 0.f, 0.f};
#pragma unroll
      for (int nf = 0; nf < 4; ++nf)
#pragma unroll
        for (int r = 0; r < 4; ++r) {
          float p = mk[nf] ? 0.f
                           : __builtin_amdgcn_exp2f((s[mf][nf][r] - mrun[mf][r]) * KE);
          s[mf][nf][r] = p;
          rs[r] += p;
        }
#pragma unroll
      for (int xm = 1; xm < 16; xm <<= 1)
#pragma unroll
        for (int r = 0; r < 4; ++r)
          rs[r] += __shfl_xor(rs[r], xm);
#pragma unroll
      for (int r = 0; r < 4; ++r)
        lrun[mf][r] = lrun[mf][r] * al[r] + rs[r];
#pragma unroll
      for (int nf = 0; nf < 4; ++nf)
#pragma unroll
        for (int r = 0; r < 4; ++r)
          o[mf][nf][r] *= al[r];
      // write P tile (C-layout -> LDS), rows are wave-private
#pragma unroll
      for (int nf = 0; nf < 4; ++nf)
#pragma unroll
        for (int r = 0; r < 4; ++r)
          Ps[(wid * 32 + mf * 16 + (lane >> 4) * 4 + r) * 64 + nf * 16 + lr] =
              f2bf(s[mf][nf][r]);
    }
    asm volatile("s_waitcnt lgkmcnt(0)" ::: "memory");

    // PV
    bf16x8 vb[4][2], pa[2][2];
#pragma unroll
    for (int nf = 0; nf < 4; ++nf)
#pragma unroll
      for (int kh = 0; kh < 2; ++kh)
        vb[nf][kh] = __builtin_bit_cast(bf16x8,
            *(const short8*)(Vts + (nf * 16 + lr) * 64 + kh * 32 + lk));
#pragma unroll
    for (int mf = 0; mf < 2; ++mf)
#pragma unroll
      for (int kh = 0; kh < 2; ++kh)
        pa[mf][kh] = __builtin_bit_cast(bf16x8,
            *(const short8*)(Ps + (wid * 32 + mf * 16 + lr) * 64 + kh * 32 + lk));
#pragma unroll
    for (int mf = 0; mf < 2; ++mf)
#pragma unroll
      for (int nf = 0; nf < 4; ++nf)
#pragma unroll
        for (int kh = 0; kh < 2; ++kh)
          o[mf][nf] = __builtin_amdgcn_mfma_f32_16x16x32_bf16(
              pa[mf][kh], vb[nf][kh], o[mf][nf], 0, 0, 0);
  }

  // epilogue: normalize and write y in [B, L, D] bf16
#pragma unroll
  for (int mf = 0; mf < 2; ++mf)
#pragma unroll
    for (int nf = 0; nf < 4; ++nf)
#pragma unroll
      for (int r = 0; r < 4; ++r) {
        int qrow = q0 + wid * 32 + mf * 16 + (lane >> 4) * 4 + r;
        float v = o[mf][nf][r] / lrun[mf][r];
        yb[((size_t)b * L_SEQ + qrow) * DIM + h * 64 + nf * 16 + lr] = f2bf(v);
      }
}

// ---------------- launch ----------------
extern "C" void kernel_launch(void* const* d_in, const int* in_sizes, int n_in,
                              void* d_out, int out_size, void* d_ws, size_t ws_size,
                              hipStream_t stream) {
  const float* x     = (const float*)d_in[0];
  const int*   mask  = (const int*)d_in[1];
  const float* wqkv  = (const float*)d_in[2];
  const float* wproj = (const float*)d_in[3];
  char* ws = (char*)d_ws;
  unsigned short* xb     = (unsigned short*)(ws + 0);          // 16 MiB
  unsigned short* wqkvb  = (unsigned short*)(ws + 16777216);   // 6 MiB
  unsigned short* wprojb = (unsigned short*)(ws + 23068672);   // 2 MiB
  unsigned short* qw     = (unsigned short*)(ws + 25165824);   // 16 MiB
  unsigned short* kw     = (unsigned short*)(ws + 41943040);   // 16 MiB
  unsigned short* vtw    = (unsigned short*)(ws + 58720256);   // 16 MiB
  unsigned short* yb     = (unsigned short*)(ws + 75497472);   // 16 MiB

  cvt_bf16<<<dim3(8388608 / 2048), 256, 0, stream>>>(x, xb, 8388608);
  cvt_bf16<<<dim3(3145728 / 2048), 256, 0, stream>>>(wqkv, wqkvb, 3145728);
  cvt_bf16<<<dim3(1048576 / 2048), 256, 0, stream>>>(wproj, wprojb, 1048576);
  gemm_qkv<<<dim3(24, 64), 256, 0, stream>>>(xb, wqkvb, qw, kw, vtw);
  attn_kernel<<<dim3(16, 64), 256, 0, stream>>>(qw, kw, vtw, mask, yb);
  gemm_proj<<<dim3(8, 64), 256, 0, stream>>>(yb, wprojb, (float*)d_out);
}

// Round 2
// 377.653 us; speedup vs baseline: 1.0941x; 1.0941x over previous
//
#include <hip/hip_runtime.h>

// Problem constants
#define L_SEQ 2048
#define DIM   1024
#define NH    16
#define HDIM  64
#define KDIM  1024   // K for both GEMMs

typedef short  short8 __attribute__((ext_vector_type(8)));
typedef __bf16 bf16x8 __attribute__((ext_vector_type(8)));
typedef float  f32x4  __attribute__((ext_vector_type(4)));

__device__ __forceinline__ unsigned short f2bf(float f) {
  unsigned u = __builtin_bit_cast(unsigned, f);
  u += 0x7fffu + ((u >> 16) & 1u);   // RNE
  return (unsigned short)(u >> 16);
}

__device__ __forceinline__ void gload16(const void* g, void* l) {
  __builtin_amdgcn_global_load_lds(
      (const __attribute__((address_space(1))) void*)g,
      (__attribute__((address_space(3))) void*)l, 16, 0, 0);
}

// ---------------- fp32 -> bf16 conversion ----------------
__global__ __launch_bounds__(256) void cvt_bf16(const float* __restrict__ src,
                                                unsigned short* __restrict__ dst,
                                                int n) {
  int i = (blockIdx.x * 256 + threadIdx.x) * 8;
  if (i >= n) return;
  f32x4 a = *(const f32x4*)(src + i);
  f32x4 b = *(const f32x4*)(src + i + 4);
  short8 o;
  o[0] = (short)f2bf(a[0]); o[1] = (short)f2bf(a[1]);
  o[2] = (short)f2bf(a[2]); o[3] = (short)f2bf(a[3]);
  o[4] = (short)f2bf(b[0]); o[5] = (short)f2bf(b[1]);
  o[6] = (short)f2bf(b[2]); o[7] = (short)f2bf(b[3]);
  *(short8*)(dst + i) = o;
}

// ---------------- 128x128 NT GEMM mainloop (m97 structure) ----------------
// A: [M,1024] row-major bf16; Bt: [N,1024] row-major bf16 (i.e. B transposed).
__device__ __forceinline__ void gemm128_mainloop(
    const unsigned short* __restrict__ A, const unsigned short* __restrict__ Bt,
    int m0, int n0, unsigned short* As, unsigned short* Bs, f32x4 (&acc)[4][4]) {
  const int t = threadIdx.x;
  const int wid = t >> 6, lane = t & 63;
  const int wm = wid >> 1, wn = wid & 1;
  const int lr = lane & 15, lk = (lane >> 4) * 8;
  for (int kt = 0; kt < KDIM / 64; ++kt) {
    __syncthreads();   // previous iteration's reads complete
#pragma unroll
    for (int i = 0; i < 4; ++i) {
      int c = i * 256 + t;               // 16B chunk id, row=c>>3
      int row = c >> 3, cc = (c & 7) * 8;
      gload16(A  + (size_t)(m0 + row) * KDIM + kt * 64 + cc, As + c * 8);
      gload16(Bt + (size_t)(n0 + row) * KDIM + kt * 64 + cc, Bs + c * 8);
    }
    asm volatile("s_waitcnt vmcnt(0)" ::: "memory");
    __syncthreads();   // all waves' loads visible
    bf16x8 af[4][2], bfv[4][2];
#pragma unroll
    for (int mf = 0; mf < 4; ++mf)
#pragma unroll
      for (int kh = 0; kh < 2; ++kh)
        af[mf][kh] = __builtin_bit_cast(bf16x8,
            *(const short8*)(As + (wm * 64 + mf * 16 + lr) * 64 + kh * 32 + lk));
#pragma unroll
    for (int nf = 0; nf < 4; ++nf)
#pragma unroll
      for (int kh = 0; kh < 2; ++kh)
        bfv[nf][kh] = __builtin_bit_cast(bf16x8,
            *(const short8*)(Bs + (wn * 64 + nf * 16 + lr) * 64 + kh * 32 + lk));
#pragma unroll
    for (int mf = 0; mf < 4; ++mf)
#pragma unroll
      for (int nf = 0; nf < 4; ++nf)
#pragma unroll
        for (int kh = 0; kh < 2; ++kh)
          acc[mf][nf] = __builtin_amdgcn_mfma_f32_16x16x32_bf16(
              af[mf][kh], bfv[nf][kh], acc[mf][nf], 0, 0, 0);
  }
}

// ---------------- GEMM1: qkv = x @ Wqkv^T, scatter into head layouts ----------------
__global__ __launch_bounds__(256) void gemm_qkv(
    const unsigned short* __restrict__ xb, const unsigned short* __restrict__ wb,
    unsigned short* __restrict__ qw, unsigned short* __restrict__ kw,
    unsigned short* __restrict__ vtw) {
  __shared__ unsigned short As[128 * 64], Bs[128 * 64];
  f32x4 acc[4][4] = {};
  const int n0 = blockIdx.x * 128, m0 = blockIdx.y * 128;
  gemm128_mainloop(xb, wb, m0, n0, As, Bs, acc);
  const int t = threadIdx.x, wid = t >> 6, lane = t & 63;
  const int wm = wid >> 1, wn = wid & 1;
#pragma unroll
  for (int mf = 0; mf < 4; ++mf)
#pragma unroll
    for (int nf = 0; nf < 4; ++nf) {
      int e = n0 + wn * 64 + nf * 16 + (lane & 15);
      int sec = e >> 10;                  // 0=Q 1=K 2=V (block-uniform)
      int h = (e & 1023) >> 6, hd = e & 63;
#pragma unroll
      for (int r = 0; r < 4; ++r) {
        int m = m0 + wm * 64 + mf * 16 + (lane >> 4) * 4 + r;
        int b = m >> 11, li = m & 2047;
        size_t bh = (size_t)(b * NH + h);
        unsigned short val = f2bf(acc[mf][nf][r]);
        if (sec == 0)      qw[(bh * L_SEQ + li) * HDIM + hd] = val;
        else if (sec == 1) kw[(bh * L_SEQ + li) * HDIM + hd] = val;
        else               vtw[(bh * HDIM + hd) * L_SEQ + li] = val;  // V^T
      }
    }
}

// ---------------- GEMM2: out = y @ Wproj^T (fp32 out) ----------------
__global__ __launch_bounds__(256) void gemm_proj(
    const unsigned short* __restrict__ yb, const unsigned short* __restrict__ wb,
    float* __restrict__ out) {
  __shared__ unsigned short As[128 * 64], Bs[128 * 64];
  f32x4 acc[4][4] = {};
  const int n0 = blockIdx.x * 128, m0 = blockIdx.y * 128;
  gemm128_mainloop(yb, wb, m0, n0, As, Bs, acc);
  const int t = threadIdx.x, wid = t >> 6, lane = t & 63;
  const int wm = wid >> 1, wn = wid & 1;
#pragma unroll
  for (int mf = 0; mf < 4; ++mf)
#pragma unroll
    for (int nf = 0; nf < 4; ++nf) {
      int e = n0 + wn * 64 + nf * 16 + (lane & 15);
#pragma unroll
      for (int r = 0; r < 4; ++r) {
        int m = m0 + wm * 64 + mf * 16 + (lane >> 4) * 4 + r;
        out[(size_t)m * DIM + e] = acc[mf][nf][r];
      }
    }
}

// ---------------- Flash attention with key-padding mask ----------------
// grid: (L/128, B*H). block 256 = 4 waves; each wave owns 32 query rows.
// LDS tiles XOR-swizzled (T2): phys_byte = row*128 + (col_byte ^ ((row&7)<<4)).
// global_load_lds writes linearly -> pre-swizzle the GLOBAL source column.
// K/Vt double-buffered with counted vmcnt (T3/T4 minimum 2-phase), raw s_barrier.
__global__ __launch_bounds__(256) void attn_kernel(
    const unsigned short* __restrict__ qw, const unsigned short* __restrict__ kw,
    const unsigned short* __restrict__ vtw, const int* __restrict__ mask,
    unsigned short* __restrict__ yb) {
  __shared__ unsigned short Ks[2][64 * 64];    // [buf][kv][hd] swizzled
  __shared__ unsigned short Vts[2][64 * 64];   // [buf][hd][kv] swizzled
  __shared__ unsigned short Ps[128 * 64];      // [q][kv] swizzled, wave-private rows
  __shared__ unsigned char  Ms[L_SEQ];         // key-pad flags for this batch row
  const int bh = blockIdx.y;
  const int q0 = blockIdx.x * 128;
  const int b = bh >> 4, h = bh & 15;
  const int t = threadIdx.x, wid = t >> 6, lane = t & 63;
  const int lr = lane & 15, lk = (lane >> 4) * 8;
  const int swr = (lr & 7) << 3;            // read-side element-XOR for rows ≡ lr (mod 8)
  const float KE = 0.18033688011112042f;    // (1/sqrt(64)) * log2(e)

  // stage mask row into LDS once (keeps the loop's VMEM = only gload16s)
  {
    const int* mrow = mask + b * L_SEQ + t * 8;
    int4 a = *(const int4*)(mrow);
    int4 c = *(const int4*)(mrow + 4);
    unsigned w0 = (unsigned)(a.x & 1) | ((unsigned)(a.y & 1) << 8) |
                  ((unsigned)(a.z & 1) << 16) | ((unsigned)(a.w & 1) << 24);
    unsigned w1 = (unsigned)(c.x & 1) | ((unsigned)(c.y & 1) << 8) |
                  ((unsigned)(c.z & 1) << 16) | ((unsigned)(c.w & 1) << 24);
    *(unsigned*)(Ms + t * 8)     = w0;
    *(unsigned*)(Ms + t * 8 + 4) = w1;
  }

  // Q fragments in registers (rows q0 + wid*32 .. +32)
  bf16x8 qf[2][2];
  const size_t qbase = (size_t)bh * L_SEQ + q0 + wid * 32;
#pragma unroll
  for (int mf = 0; mf < 2; ++mf)
#pragma unroll
    for (int kh = 0; kh < 2; ++kh)
      qf[mf][kh] = __builtin_bit_cast(bf16x8,
          *(const short8*)(qw + (qbase + mf * 16 + lr) * HDIM + kh * 32 + lk));

  f32x4 o[2][4] = {};
  float mrun[2][4], lrun[2][4];
#pragma unroll
  for (int mf = 0; mf < 2; ++mf)
#pragma unroll
    for (int r = 0; r < 4; ++r) { mrun[mf][r] = -3.0e38f; lrun[mf][r] = 0.f; }

  // staging: 4 gload16 per thread per tile; source col pre-swizzled so a
  // swizzled READ of (row, col) returns the right data.
  auto stage = [&](int buf, int kt) {
#pragma unroll
    for (int i = 0; i < 2; ++i) {
      int c = i * 256 + t;
      int row = c >> 3;
      int cs = ((c & 7) ^ (row & 7)) * 8;   // inverse-swizzled source column (elems)
      gload16(kw  + ((size_t)bh * L_SEQ + kt * 64 + row) * HDIM + cs, &Ks[buf][c * 8]);
      gload16(vtw + ((size_t)bh * HDIM + row) * L_SEQ + kt * 64 + cs, &Vts[buf][c * 8]);
    }
  };

  asm volatile("s_waitcnt lgkmcnt(0)" ::: "memory");  // Ms writes complete (this wave)
  stage(0, 0);
  int cur = 0;

  for (int kt = 0; kt < L_SEQ / 64; ++kt) {
    const int kv0 = kt * 64;
    if (kt + 1 < L_SEQ / 64) {
      stage(cur ^ 1, kt + 1);                          // prefetch next tile
      asm volatile("s_waitcnt vmcnt(4)" ::: "memory"); // wait CURRENT only (4 newest in flight)
    } else {
      asm volatile("s_waitcnt vmcnt(0)" ::: "memory");
    }
    __builtin_amdgcn_s_barrier();        // raw barrier: does NOT drain vmcnt
    __builtin_amdgcn_sched_barrier(0);   // pin: no hoisting of reads above barrier

    int mk[4];
#pragma unroll
    for (int nf = 0; nf < 4; ++nf)
      mk[nf] = Ms[kv0 + nf * 16 + lr];

    // QK^T (swizzled K reads)
    const unsigned short* Kc = Ks[cur];
    bf16x8 kf[4][2];
#pragma unroll
    for (int nf = 0; nf < 4; ++nf)
#pragma unroll
      for (int kh = 0; kh < 2; ++kh)
        kf[nf][kh] = __builtin_bit_cast(bf16x8,
            *(const short8*)(Kc + (nf * 16 + lr) * 64 + ((kh * 32 + lk) ^ swr)));
    f32x4 s[2][4] = {};
#pragma unroll
    for (int mf = 0; mf < 2; ++mf)
#pragma unroll
      for (int nf = 0; nf < 4; ++nf)
#pragma unroll
        for (int kh = 0; kh < 2; ++kh)
          s[mf][nf] = __builtin_amdgcn_mfma_f32_16x16x32_bf16(
              qf[mf][kh], kf[nf][kh], s[mf][nf], 0, 0, 0);

    // online softmax per mf
#pragma unroll
    for (int mf = 0; mf < 2; ++mf) {
      float mt[4];
#pragma unroll
      for (int r = 0; r < 4; ++r) {
        float v0 = mk[0] ? -3.0e38f : s[mf][0][r];
        float v1 = mk[1] ? -3.0e38f : s[mf][1][r];
        float v2 = mk[2] ? -3.0e38f : s[mf][2][r];
        float v3 = mk[3] ? -3.0e38f : s[mf][3][r];
        mt[r] = fmaxf(fmaxf(v0, v1), fmaxf(v2, v3));
      }
#pragma unroll
      for (int xm = 1; xm < 16; xm <<= 1)
#pragma unroll
        for (int r = 0; r < 4; ++r)
          mt[r] = fmaxf(mt[r], __shfl_xor(mt[r], xm));
      float al[4];
#pragma unroll
      for (int r = 0; r < 4; ++r) {
        float mn = fmaxf(mrun[mf][r], mt[r]);
        al[r] = __builtin_amdgcn_exp2f((mrun[mf][r] - mn) * KE);
        mrun[mf][r] = mn;
      }
      float rs[4] = {0.f, 0.f, 0.f, 0.f};
#pragma unroll
      for (int nf = 0; nf < 4; ++nf)
#pragma unroll
        for (int r = 0; r < 4; ++r) {
          float p = mk[nf] ? 0.f
                           : __builtin_amdgcn_exp2f((s[mf][nf][r] - mrun[mf][r]) * KE);
          s[mf][nf][r] = p;
          rs[r] += p;
        }
#pragma unroll
      for (int xm = 1; xm < 16; xm <<= 1)
#pragma unroll
        for (int r = 0; r < 4; ++r)
          rs[r] += __shfl_xor(rs[r], xm);
#pragma unroll
      for (int r = 0; r < 4; ++r)
        lrun[mf][r] = lrun[mf][r] * al[r] + rs[r];
#pragma unroll
      for (int nf = 0; nf < 4; ++nf)
#pragma unroll
        for (int r = 0; r < 4; ++r)
          o[mf][nf][r] *= al[r];
      // write P tile (C-layout -> LDS, swizzled), rows are wave-private
#pragma unroll
      for (int nf = 0; nf < 4; ++nf)
#pragma unroll
        for (int r = 0; r < 4; ++r) {
          int q = wid * 32 + mf * 16 + (lane >> 4) * 4 + r;
          Ps[q * 64 + ((nf * 16 + lr) ^ ((q & 7) << 3))] = f2bf(s[mf][nf][r]);
        }
    }
    asm volatile("s_waitcnt lgkmcnt(0)" ::: "memory");
    __builtin_amdgcn_sched_barrier(0);

    // PV (swizzled Vt and P reads)
    const unsigned short* Vc = Vts[cur];
    bf16x8 vb[4][2], pa[2][2];
#pragma unroll
    for (int nf = 0; nf < 4; ++nf)
#pragma unroll
      for (int kh = 0; kh < 2; ++kh)
        vb[nf][kh] = __builtin_bit_cast(bf16x8,
            *(const short8*)(Vc + (nf * 16 + lr) * 64 + ((kh * 32 + lk) ^ swr)));
#pragma unroll
    for (int mf = 0; mf < 2; ++mf)
#pragma unroll
      for (int kh = 0; kh < 2; ++kh)
        pa[mf][kh] = __builtin_bit_cast(bf16x8,
            *(const short8*)(Ps + (wid * 32 + mf * 16 + lr) * 64 +
                             ((kh * 32 + lk) ^ swr)));
#pragma unroll
    for (int mf = 0; mf < 2; ++mf)
#pragma unroll
      for (int nf = 0; nf < 4; ++nf)
#pragma unroll
        for (int kh = 0; kh < 2; ++kh)
          o[mf][nf] = __builtin_amdgcn_mfma_f32_16x16x32_bf16(
              pa[mf][kh], vb[nf][kh], o[mf][nf], 0, 0, 0);

    __builtin_amdgcn_sched_barrier(0);   // all LDS reads of buf[cur] retired above
    __builtin_amdgcn_s_barrier();        // before anyone overwrites buf[cur^1->cur]
    cur ^= 1;
  }

  // epilogue: normalize and write y in [B, L, D] bf16
#pragma unroll
  for (int mf = 0; mf < 2; ++mf)
#pragma unroll
    for (int nf = 0; nf < 4; ++nf)
#pragma unroll
      for (int r = 0; r < 4; ++r) {
        int qrow = q0 + wid * 32 + mf * 16 + (lane >> 4) * 4 + r;
        float v = o[mf][nf][r] / lrun[mf][r];
        yb[((size_t)b * L_SEQ + qrow) * DIM + h * 64 + nf * 16 + lr] = f2bf(v);
      }
}

// ---------------- launch ----------------
extern "C" void kernel_launch(void* const* d_in, const int* in_sizes, int n_in,
                              void* d_out, int out_size, void* d_ws, size_t ws_size,
                              hipStream_t stream) {
  const float* x     = (const float*)d_in[0];
  const int*   mask  = (const int*)d_in[1];
  const float* wqkv  = (const float*)d_in[2];
  const float* wproj = (const float*)d_in[3];
  char* ws = (char*)d_ws;
  unsigned short* xb     = (unsigned short*)(ws + 0);          // 16 MiB
  unsigned short* wqkvb  = (unsigned short*)(ws + 16777216);   // 6 MiB
  unsigned short* wprojb = (unsigned short*)(ws + 23068672);   // 2 MiB
  unsigned short* qw     = (unsigned short*)(ws + 25165824);   // 16 MiB
  unsigned short* kw     = (unsigned short*)(ws + 41943040);   // 16 MiB
  unsigned short* vtw    = (unsigned short*)(ws + 58720256);   // 16 MiB
  unsigned short* yb     = (unsigned short*)(ws + 75497472);   // 16 MiB

  cvt_bf16<<<dim3(8388608 / 2048), 256, 0, stream>>>(x, xb, 8388608);
  cvt_bf16<<<dim3(3145728 / 2048), 256, 0, stream>>>(wqkv, wqkvb, 3145728);
  cvt_bf16<<<dim3(1048576 / 2048), 256, 0, stream>>>(wproj, wprojb, 1048576);
  gemm_qkv<<<dim3(24, 64), 256, 0, stream>>>(xb, wqkvb, qw, kw, vtw);
  attn_kernel<<<dim3(16, 64), 256, 0, stream>>>(qw, kw, vtw, mask, yb);
  gemm_proj<<<dim3(8, 64), 256, 0, stream>>>(yb, wprojb, (float*)d_out);
}

// Round 3
// 282.682 us; speedup vs baseline: 1.4616x; 1.3360x over previous
//
#include <hip/hip_runtime.h>

// Problem constants
#define L_SEQ 2048
#define DIM   1024
#define NH    16
#define HDIM  64
#define KDIM  1024   // K for both GEMMs

typedef short  short8 __attribute__((ext_vector_type(8)));
typedef __bf16 bf16x8 __attribute__((ext_vector_type(8)));
typedef __bf16 bf16x4 __attribute__((ext_vector_type(4)));
typedef float  f32x4  __attribute__((ext_vector_type(4)));

__device__ __forceinline__ unsigned short f2bf(float f) {
  unsigned u = __builtin_bit_cast(unsigned, f);
  u += 0x7fffu + ((u >> 16) & 1u);   // RNE
  return (unsigned short)(u >> 16);
}

__device__ __forceinline__ void gload16(const void* g, void* l) {
  __builtin_amdgcn_global_load_lds(
      (const __attribute__((address_space(1))) void*)g,
      (__attribute__((address_space(3))) void*)l, 16, 0, 0);
}

// ---------------- fp32 -> bf16 conversion ----------------
__global__ __launch_bounds__(256) void cvt_bf16(const float* __restrict__ src,
                                                unsigned short* __restrict__ dst,
                                                int n) {
  int i = (blockIdx.x * 256 + threadIdx.x) * 8;
  if (i >= n) return;
  f32x4 a = *(const f32x4*)(src + i);
  f32x4 b = *(const f32x4*)(src + i + 4);
  short8 o;
  o[0] = (short)f2bf(a[0]); o[1] = (short)f2bf(a[1]);
  o[2] = (short)f2bf(a[2]); o[3] = (short)f2bf(a[3]);
  o[4] = (short)f2bf(b[0]); o[5] = (short)f2bf(b[1]);
  o[6] = (short)f2bf(b[2]); o[7] = (short)f2bf(b[3]);
  *(short8*)(dst + i) = o;
}

// ---------------- 128x128 NT GEMM mainloop (m97 structure) ----------------
__device__ __forceinline__ void gemm128_mainloop(
    const unsigned short* __restrict__ A, const unsigned short* __restrict__ Bt,
    int m0, int n0, unsigned short* As, unsigned short* Bs, f32x4 (&acc)[4][4]) {
  const int t = threadIdx.x;
  const int wid = t >> 6, lane = t & 63;
  const int wm = wid >> 1, wn = wid & 1;
  const int lr = lane & 15, lk = (lane >> 4) * 8;
  for (int kt = 0; kt < KDIM / 64; ++kt) {
    __syncthreads();
#pragma unroll
    for (int i = 0; i < 4; ++i) {
      int c = i * 256 + t;
      int row = c >> 3, cc = (c & 7) * 8;
      gload16(A  + (size_t)(m0 + row) * KDIM + kt * 64 + cc, As + c * 8);
      gload16(Bt + (size_t)(n0 + row) * KDIM + kt * 64 + cc, Bs + c * 8);
    }
    asm volatile("s_waitcnt vmcnt(0)" ::: "memory");
    __syncthreads();
    bf16x8 af[4][2], bfv[4][2];
#pragma unroll
    for (int mf = 0; mf < 4; ++mf)
#pragma unroll
      for (int kh = 0; kh < 2; ++kh)
        af[mf][kh] = __builtin_bit_cast(bf16x8,
            *(const short8*)(As + (wm * 64 + mf * 16 + lr) * 64 + kh * 32 + lk));
#pragma unroll
    for (int nf = 0; nf < 4; ++nf)
#pragma unroll
      for (int kh = 0; kh < 2; ++kh)
        bfv[nf][kh] = __builtin_bit_cast(bf16x8,
            *(const short8*)(Bs + (wn * 64 + nf * 16 + lr) * 64 + kh * 32 + lk));
#pragma unroll
    for (int mf = 0; mf < 4; ++mf)
#pragma unroll
      for (int nf = 0; nf < 4; ++nf)
#pragma unroll
        for (int kh = 0; kh < 2; ++kh)
          acc[mf][nf] = __builtin_amdgcn_mfma_f32_16x16x32_bf16(
              af[mf][kh], bfv[nf][kh], acc[mf][nf], 0, 0, 0);
  }
}

// ---------------- GEMM1: qkv = x @ Wqkv^T, scatter into head layouts ----------------
__global__ __launch_bounds__(256) void gemm_qkv(
    const unsigned short* __restrict__ xb, const unsigned short* __restrict__ wb,
    unsigned short* __restrict__ qw, unsigned short* __restrict__ kw,
    unsigned short* __restrict__ vtw) {
  __shared__ unsigned short As[128 * 64], Bs[128 * 64];
  f32x4 acc[4][4] = {};
  const int n0 = blockIdx.x * 128, m0 = blockIdx.y * 128;
  gemm128_mainloop(xb, wb, m0, n0, As, Bs, acc);
  const int t = threadIdx.x, wid = t >> 6, lane = t & 63;
  const int wm = wid >> 1, wn = wid & 1;
#pragma unroll
  for (int mf = 0; mf < 4; ++mf)
#pragma unroll
    for (int nf = 0; nf < 4; ++nf) {
      int e = n0 + wn * 64 + nf * 16 + (lane & 15);
      int sec = e >> 10;
      int h = (e & 1023) >> 6, hd = e & 63;
#pragma unroll
      for (int r = 0; r < 4; ++r) {
        int m = m0 + wm * 64 + mf * 16 + (lane >> 4) * 4 + r;
        int b = m >> 11, li = m & 2047;
        size_t bh = (size_t)(b * NH + h);
        unsigned short val = f2bf(acc[mf][nf][r]);
        if (sec == 0)      qw[(bh * L_SEQ + li) * HDIM + hd] = val;
        else if (sec == 1) kw[(bh * L_SEQ + li) * HDIM + hd] = val;
        else               vtw[(bh * HDIM + hd) * L_SEQ + li] = val;  // V^T
      }
    }
}

// ---------------- GEMM2: out = y @ Wproj^T (fp32 out) ----------------
__global__ __launch_bounds__(256) void gemm_proj(
    const unsigned short* __restrict__ yb, const unsigned short* __restrict__ wb,
    float* __restrict__ out) {
  __shared__ unsigned short As[128 * 64], Bs[128 * 64];
  f32x4 acc[4][4] = {};
  const int n0 = blockIdx.x * 128, m0 = blockIdx.y * 128;
  gemm128_mainloop(yb, wb, m0, n0, As, Bs, acc);
  const int t = threadIdx.x, wid = t >> 6, lane = t & 63;
  const int wm = wid >> 1, wn = wid & 1;
#pragma unroll
  for (int mf = 0; mf < 4; ++mf)
#pragma unroll
    for (int nf = 0; nf < 4; ++nf) {
      int e = n0 + wn * 64 + nf * 16 + (lane & 15);
#pragma unroll
      for (int r = 0; r < 4; ++r) {
        int m = m0 + wm * 64 + mf * 16 + (lane >> 4) * 4 + r;
        out[(size_t)m * DIM + e] = acc[mf][nf][r];
      }
    }
}

// ---------------- Flash attention, swapped-QK^T (T12 structure) ----------------
// grid: (L/128, B*H). block 256 = 4 waves; each wave owns 32 query rows.
// QK^T computed as mfma(K, Q) -> S^T: lane owns ONE q-column (q = lane&15 per
// 16-row fragment), kv spread over {nf, lane>>4, reg}. Softmax reductions are
// in-lane trees + 2 shuffles. Mask folded in as a bias-add (bf16 bias in LDS).
// PV: O^T = mfma(Vt, P) with P through a swizzled LDS round-trip (b64 writes).
__global__ __launch_bounds__(256) void attn_kernel(
    const unsigned short* __restrict__ qw, const unsigned short* __restrict__ kw,
    const unsigned short* __restrict__ vtw, const int* __restrict__ mask,
    unsigned short* __restrict__ yb) {
  __shared__ unsigned short Ks[2][64 * 64];    // [buf][kv][hd] swizzled
  __shared__ unsigned short Vts[2][64 * 64];   // [buf][hd][kv] swizzled
  __shared__ unsigned short Ps[128 * 64];      // [q][kv] swizzled, wave-private rows
  __shared__ __bf16        BiasL[L_SEQ];       // 0 or -1e30 per key
  const int bh = blockIdx.y;
  const int q0 = blockIdx.x * 128;
  const int b = bh >> 4, h = bh & 15;
  const int t = threadIdx.x, wid = t >> 6, lane = t & 63;
  const int lr = lane & 15, lk = (lane >> 4) * 8, g4 = (lane >> 4) * 4;
  const int swr = (lr & 7) << 3;            // read/write-side element XOR
  const float KE = 0.18033688011112042f;    // (1/sqrt(64)) * log2(e)

  // stage mask row as additive bias (bf16) into LDS once
  {
    const int* mrow = mask + b * L_SEQ + t * 8;
    int4 a = *(const int4*)(mrow);
    int4 c2 = *(const int4*)(mrow + 4);
    const __bf16 BN = (__bf16)(-1.0e30f), BZ = (__bf16)(0.0f);
    bf16x8 bv;
    bv[0] = a.x ? BN : BZ;  bv[1] = a.y ? BN : BZ;
    bv[2] = a.z ? BN : BZ;  bv[3] = a.w ? BN : BZ;
    bv[4] = c2.x ? BN : BZ; bv[5] = c2.y ? BN : BZ;
    bv[6] = c2.z ? BN : BZ; bv[7] = c2.w ? BN : BZ;
    *(bf16x8*)(&BiasL[t * 8]) = bv;
  }

  // Q fragments (B-operand): rows q = q0 + wid*32 + qi*16 + lr, k = d
  bf16x8 qf[2][2];
  const size_t qbase = (size_t)bh * L_SEQ + q0 + wid * 32;
#pragma unroll
  for (int qi = 0; qi < 2; ++qi)
#pragma unroll
    for (int kh = 0; kh < 2; ++kh)
      qf[qi][kh] = __builtin_bit_cast(bf16x8,
          *(const short8*)(qw + (qbase + qi * 16 + lr) * HDIM + kh * 32 + lk));

  f32x4 o[2][4] = {};                       // O^T: d = df*16+g*4+r, q = qi*16+lr
  float mrun[2] = {-3.0e38f, -3.0e38f};
  float lrun[2] = {0.f, 0.f};

  auto stage = [&](int buf, int kt) {
#pragma unroll
    for (int i = 0; i < 2; ++i) {
      int c = i * 256 + t;
      int row = c >> 3;
      int cs = ((c & 7) ^ (row & 7)) * 8;   // inverse-swizzled source column
      gload16(kw  + ((size_t)bh * L_SEQ + kt * 64 + row) * HDIM + cs, &Ks[buf][c * 8]);
      gload16(vtw + ((size_t)bh * HDIM + row) * L_SEQ + kt * 64 + cs, &Vts[buf][c * 8]);
    }
  };

  asm volatile("s_waitcnt lgkmcnt(0)" ::: "memory");  // bias writes drained
  stage(0, 0);
  int cur = 0;

  for (int kt = 0; kt < L_SEQ / 64; ++kt) {
    const int kv0 = kt * 64;
    if (kt + 1 < L_SEQ / 64) {
      stage(cur ^ 1, kt + 1);                          // prefetch next tile
      asm volatile("s_waitcnt vmcnt(4)" ::: "memory"); // current tile landed
    } else {
      asm volatile("s_waitcnt vmcnt(0)" ::: "memory");
    }
    __builtin_amdgcn_s_barrier();
    __builtin_amdgcn_sched_barrier(0);

    // ---- QK^T: s[qi][nf] = S^T fragment, kv = nf*16+g*4+r, q = qi*16+lr ----
    const unsigned short* Kc = Ks[cur];
    f32x4 s[2][4] = {};
    __builtin_amdgcn_s_setprio(1);
#pragma unroll
    for (int nf = 0; nf < 4; ++nf) {
      bf16x8 k0 = __builtin_bit_cast(bf16x8,
          *(const short8*)(Kc + (nf * 16 + lr) * 64 + ((0 + lk) ^ swr)));
      bf16x8 k1 = __builtin_bit_cast(bf16x8,
          *(const short8*)(Kc + (nf * 16 + lr) * 64 + ((32 + lk) ^ swr)));
      s[0][nf] = __builtin_amdgcn_mfma_f32_16x16x32_bf16(k0, qf[0][0], s[0][nf], 0, 0, 0);
      s[0][nf] = __builtin_amdgcn_mfma_f32_16x16x32_bf16(k1, qf[0][1], s[0][nf], 0, 0, 0);
      s[1][nf] = __builtin_amdgcn_mfma_f32_16x16x32_bf16(k0, qf[1][0], s[1][nf], 0, 0, 0);
      s[1][nf] = __builtin_amdgcn_mfma_f32_16x16x32_bf16(k1, qf[1][1], s[1][nf], 0, 0, 0);
    }
    __builtin_amdgcn_s_setprio(0);

    // ---- mask bias (branchless) ----
#pragma unroll
    for (int nf = 0; nf < 4; ++nf) {
      bf16x4 bv4 = *(const bf16x4*)(&BiasL[kv0 + nf * 16 + g4]);
      f32x4 bb = {(float)bv4[0], (float)bv4[1], (float)bv4[2], (float)bv4[3]};
      s[0][nf] += bb;
      s[1][nf] += bb;
    }

    // ---- tile max per q-column: in-lane tree + 2 shuffles ----
    float pmax[2];
#pragma unroll
    for (int qi = 0; qi < 2; ++qi) {
      float a0 = fmaxf(fmaxf(s[qi][0][0], s[qi][0][1]), fmaxf(s[qi][0][2], s[qi][0][3]));
      float a1 = fmaxf(fmaxf(s[qi][1][0], s[qi][1][1]), fmaxf(s[qi][1][2], s[qi][1][3]));
      float a2 = fmaxf(fmaxf(s[qi][2][0], s[qi][2][1]), fmaxf(s[qi][2][2], s[qi][2][3]));
      float a3 = fmaxf(fmaxf(s[qi][3][0], s[qi][3][1]), fmaxf(s[qi][3][2], s[qi][3][3]));
      float mm = fmaxf(fmaxf(a0, a1), fmaxf(a2, a3));
      mm = fmaxf(mm, __shfl_xor(mm, 16));
      mm = fmaxf(mm, __shfl_xor(mm, 32));
      pmax[qi] = mm;
    }

    // ---- defer-max rescale (T13, THR=8 in raw-score units) ----
    bool need = (pmax[0] > mrun[0] + 8.0f) || (pmax[1] > mrun[1] + 8.0f);
    if (__any(need)) {
#pragma unroll
      for (int qi = 0; qi < 2; ++qi) {
        float mn = fmaxf(mrun[qi], pmax[qi]);
        float al = __builtin_amdgcn_exp2f((mrun[qi] - mn) * KE);
        mrun[qi] = mn;
        lrun[qi] *= al;
#pragma unroll
        for (int df = 0; df < 4; ++df) o[qi][df] *= al;
      }
    }

    // ---- exp + row-sum + P write (bf16x4, swizzled, wave-private rows) ----
#pragma unroll
    for (int qi = 0; qi < 2; ++qi) {
      float mk_ = mrun[qi] * KE;
      f32x4 rs4 = {0.f, 0.f, 0.f, 0.f};
      int q = wid * 32 + qi * 16 + lr;
#pragma unroll
      for (int nf = 0; nf < 4; ++nf) {
#pragma unroll
        for (int r = 0; r < 4; ++r)
          s[qi][nf][r] = __builtin_amdgcn_exp2f(s[qi][nf][r] * KE - mk_);
        rs4 += s[qi][nf];
        bf16x4 pk = {(__bf16)s[qi][nf][0], (__bf16)s[qi][nf][1],
                     (__bf16)s[qi][nf][2], (__bf16)s[qi][nf][3]};
        *(bf16x4*)(Ps + q * 64 + ((nf * 16 + g4) ^ swr)) = pk;
      }
      float rsum = (rs4[0] + rs4[1]) + (rs4[2] + rs4[3]);
      rsum += __shfl_xor(rsum, 16);
      rsum += __shfl_xor(rsum, 32);
      lrun[qi] += rsum;
    }
    asm volatile("s_waitcnt lgkmcnt(0)" ::: "memory");
    __builtin_amdgcn_sched_barrier(0);

    // ---- PV: O^T += mfma(Vt, P) ----
    const unsigned short* Vc = Vts[cur];
    bf16x8 pb[2][2];
#pragma unroll
    for (int qi = 0; qi < 2; ++qi)
#pragma unroll
      for (int kh = 0; kh < 2; ++kh)
        pb[qi][kh] = __builtin_bit_cast(bf16x8,
            *(const short8*)(Ps + (wid * 32 + qi * 16 + lr) * 64 +
                             ((kh * 32 + lk) ^ swr)));
    __builtin_amdgcn_s_setprio(1);
#pragma unroll
    for (int df = 0; df < 4; ++df) {
      bf16x8 v0 = __builtin_bit_cast(bf16x8,
          *(const short8*)(Vc + (df * 16 + lr) * 64 + ((0 + lk) ^ swr)));
      bf16x8 v1 = __builtin_bit_cast(bf16x8,
          *(const short8*)(Vc + (df * 16 + lr) * 64 + ((32 + lk) ^ swr)));
      o[0][df] = __builtin_amdgcn_mfma_f32_16x16x32_bf16(v0, pb[0][0], o[0][df], 0, 0, 0);
      o[0][df] = __builtin_amdgcn_mfma_f32_16x16x32_bf16(v1, pb[0][1], o[0][df], 0, 0, 0);
      o[1][df] = __builtin_amdgcn_mfma_f32_16x16x32_bf16(v0, pb[1][0], o[1][df], 0, 0, 0);
      o[1][df] = __builtin_amdgcn_mfma_f32_16x16x32_bf16(v1, pb[1][1], o[1][df], 0, 0, 0);
    }
    __builtin_amdgcn_s_setprio(0);

    __builtin_amdgcn_sched_barrier(0);   // all LDS reads of buf[cur] retired
    __builtin_amdgcn_s_barrier();        // before next stage overwrites it
    cur ^= 1;
  }

  // epilogue: normalize, write y[B, L, D] bf16 (b64 stores)
#pragma unroll
  for (int qi = 0; qi < 2; ++qi) {
    float inv = 1.0f / lrun[qi];
    int q = q0 + wid * 32 + qi * 16 + lr;
#pragma unroll
    for (int df = 0; df < 4; ++df) {
      bf16x4 pk = {(__bf16)(o[qi][df][0] * inv), (__bf16)(o[qi][df][1] * inv),
                   (__bf16)(o[qi][df][2] * inv), (__bf16)(o[qi][df][3] * inv)};
      *(bf16x4*)(yb + ((size_t)b * L_SEQ + q) * DIM + h * 64 + df * 16 + g4) = pk;
    }
  }
}

// ---------------- launch ----------------
extern "C" void kernel_launch(void* const* d_in, const int* in_sizes, int n_in,
                              void* d_out, int out_size, void* d_ws, size_t ws_size,
                              hipStream_t stream) {
  const float* x     = (const float*)d_in[0];
  const int*   mask  = (const int*)d_in[1];
  const float* wqkv  = (const float*)d_in[2];
  const float* wproj = (const float*)d_in[3];
  char* ws = (char*)d_ws;
  unsigned short* xb     = (unsigned short*)(ws + 0);          // 16 MiB
  unsigned short* wqkvb  = (unsigned short*)(ws + 16777216);   // 6 MiB
  unsigned short* wprojb = (unsigned short*)(ws + 23068672);   // 2 MiB
  unsigned short* qw     = (unsigned short*)(ws + 25165824);   // 16 MiB
  unsigned short* kw     = (unsigned short*)(ws + 41943040);   // 16 MiB
  unsigned short* vtw    = (unsigned short*)(ws + 58720256);   // 16 MiB
  unsigned short* yb     = (unsigned short*)(ws + 75497472);   // 16 MiB

  cvt_bf16<<<dim3(8388608 / 2048), 256, 0, stream>>>(x, xb, 8388608);
  cvt_bf16<<<dim3(3145728 / 2048), 256, 0, stream>>>(wqkv, wqkvb, 3145728);
  cvt_bf16<<<dim3(1048576 / 2048), 256, 0, stream>>>(wproj, wprojb, 1048576);
  gemm_qkv<<<dim3(24, 64), 256, 0, stream>>>(xb, wqkvb, qw, kw, vtw);
  attn_kernel<<<dim3(16, 64), 256, 0, stream>>>(qw, kw, vtw, mask, yb);
  gemm_proj<<<dim3(8, 64), 256, 0, stream>>>(yb, wprojb, (float*)d_out);
}

// Round 4
// 256.293 us; speedup vs baseline: 1.6121x; 1.1030x over previous
//
#include <hip/hip_runtime.h>

// Problem constants
#define L_SEQ 2048
#define DIM   1024
#define NH    16
#define HDIM  64
#define KDIM  1024   // K for both GEMMs

typedef short  short8 __attribute__((ext_vector_type(8)));
typedef __bf16 bf16x8 __attribute__((ext_vector_type(8)));
typedef __bf16 bf16x4 __attribute__((ext_vector_type(4)));
typedef float  f32x4  __attribute__((ext_vector_type(4)));
typedef unsigned u32x4 __attribute__((ext_vector_type(4)));

__device__ __forceinline__ unsigned short f2bf(float f) {
  unsigned u = __builtin_bit_cast(unsigned, f);
  u += 0x7fffu + ((u >> 16) & 1u);   // RNE
  return (unsigned short)(u >> 16);
}

__device__ __forceinline__ void gload16(const void* g, void* l) {
  __builtin_amdgcn_global_load_lds(
      (const __attribute__((address_space(1))) void*)g,
      (__attribute__((address_space(3))) void*)l, 16, 0, 0);
}

// pack two f32 -> one u32 of 2 bf16 (lo = a, hi = b)
__device__ __forceinline__ unsigned cvtpk(float a, float b) {
  unsigned r;
  asm("v_cvt_pk_bf16_f32 %0, %1, %2" : "=v"(r) : "v"(a), "v"(b));
  return r;
}
// after call: a = {a0,a2,b0,b2}, b = {a1,a3,b1,b3} (16-lane chunks)
__device__ __forceinline__ void xchg(unsigned &a, unsigned &b) {
  asm("v_permlane32_swap_b32 %0, %1" : "+v"(a), "+v"(b));   // a={a0,a1,b0,b1} b={a2,a3,b2,b3}
  asm("v_permlane16_swap_b32 %0, %1" : "+v"(a), "+v"(b));   // a={a0,a2,b0,b2} b={a1,a3,b1,b3}
}

// ---------------- fp32 -> bf16 conversion ----------------
__global__ __launch_bounds__(256) void cvt_bf16(const float* __restrict__ src,
                                                unsigned short* __restrict__ dst,
                                                int n) {
  int i = (blockIdx.x * 256 + threadIdx.x) * 8;
  if (i >= n) return;
  f32x4 a = *(const f32x4*)(src + i);
  f32x4 b = *(const f32x4*)(src + i + 4);
  short8 o;
  o[0] = (short)f2bf(a[0]); o[1] = (short)f2bf(a[1]);
  o[2] = (short)f2bf(a[2]); o[3] = (short)f2bf(a[3]);
  o[4] = (short)f2bf(b[0]); o[5] = (short)f2bf(b[1]);
  o[6] = (short)f2bf(b[2]); o[7] = (short)f2bf(b[3]);
  *(short8*)(dst + i) = o;
}

// ---------------- 128x128 NT GEMM mainloop (m97 structure) ----------------
__device__ __forceinline__ void gemm128_mainloop(
    const unsigned short* __restrict__ A, const unsigned short* __restrict__ Bt,
    int m0, int n0, unsigned short* As, unsigned short* Bs, f32x4 (&acc)[4][4]) {
  const int t = threadIdx.x;
  const int wid = t >> 6, lane = t & 63;
  const int wm = wid >> 1, wn = wid & 1;
  const int lr = lane & 15, lk = (lane >> 4) * 8;
  for (int kt = 0; kt < KDIM / 64; ++kt) {
    __syncthreads();
#pragma unroll
    for (int i = 0; i < 4; ++i) {
      int c = i * 256 + t;
      int row = c >> 3, cc = (c & 7) * 8;
      gload16(A  + (size_t)(m0 + row) * KDIM + kt * 64 + cc, As + c * 8);
      gload16(Bt + (size_t)(n0 + row) * KDIM + kt * 64 + cc, Bs + c * 8);
    }
    asm volatile("s_waitcnt vmcnt(0)" ::: "memory");
    __syncthreads();
    bf16x8 af[4][2], bfv[4][2];
#pragma unroll
    for (int mf = 0; mf < 4; ++mf)
#pragma unroll
      for (int kh = 0; kh < 2; ++kh)
        af[mf][kh] = __builtin_bit_cast(bf16x8,
            *(const short8*)(As + (wm * 64 + mf * 16 + lr) * 64 + kh * 32 + lk));
#pragma unroll
    for (int nf = 0; nf < 4; ++nf)
#pragma unroll
      for (int kh = 0; kh < 2; ++kh)
        bfv[nf][kh] = __builtin_bit_cast(bf16x8,
            *(const short8*)(Bs + (wn * 64 + nf * 16 + lr) * 64 + kh * 32 + lk));
#pragma unroll
    for (int mf = 0; mf < 4; ++mf)
#pragma unroll
      for (int nf = 0; nf < 4; ++nf)
#pragma unroll
        for (int kh = 0; kh < 2; ++kh)
          acc[mf][nf] = __builtin_amdgcn_mfma_f32_16x16x32_bf16(
              af[mf][kh], bfv[nf][kh], acc[mf][nf], 0, 0, 0);
  }
}

// ---------------- GEMM1: qkv = x @ Wqkv^T, scatter into head layouts ----------------
__global__ __launch_bounds__(256) void gemm_qkv(
    const unsigned short* __restrict__ xb, const unsigned short* __restrict__ wb,
    unsigned short* __restrict__ qw, unsigned short* __restrict__ kw,
    unsigned short* __restrict__ vtw) {
  __shared__ unsigned short As[128 * 64], Bs[128 * 64];
  f32x4 acc[4][4] = {};
  const int n0 = blockIdx.x * 128, m0 = blockIdx.y * 128;
  gemm128_mainloop(xb, wb, m0, n0, As, Bs, acc);
  const int t = threadIdx.x, wid = t >> 6, lane = t & 63;
  const int wm = wid >> 1, wn = wid & 1;
#pragma unroll
  for (int mf = 0; mf < 4; ++mf)
#pragma unroll
    for (int nf = 0; nf < 4; ++nf) {
      int e = n0 + wn * 64 + nf * 16 + (lane & 15);
      int sec = e >> 10;
      int h = (e & 1023) >> 6, hd = e & 63;
#pragma unroll
      for (int r = 0; r < 4; ++r) {
        int m = m0 + wm * 64 + mf * 16 + (lane >> 4) * 4 + r;
        int b = m >> 11, li = m & 2047;
        size_t bh = (size_t)(b * NH + h);
        unsigned short val = f2bf(acc[mf][nf][r]);
        if (sec == 0)      qw[(bh * L_SEQ + li) * HDIM + hd] = val;
        else if (sec == 1) kw[(bh * L_SEQ + li) * HDIM + hd] = val;
        else               vtw[(bh * HDIM + hd) * L_SEQ + li] = val;  // V^T
      }
    }
}

// ---------------- GEMM2: out = y @ Wproj^T (fp32 out) ----------------
__global__ __launch_bounds__(256) void gemm_proj(
    const unsigned short* __restrict__ yb, const unsigned short* __restrict__ wb,
    float* __restrict__ out) {
  __shared__ unsigned short As[128 * 64], Bs[128 * 64];
  f32x4 acc[4][4] = {};
  const int n0 = blockIdx.x * 128, m0 = blockIdx.y * 128;
  gemm128_mainloop(yb, wb, m0, n0, As, Bs, acc);
  const int t = threadIdx.x, wid = t >> 6, lane = t & 63;
  const int wm = wid >> 1, wn = wid & 1;
#pragma unroll
  for (int mf = 0; mf < 4; ++mf)
#pragma unroll
    for (int nf = 0; nf < 4; ++nf) {
      int e = n0 + wn * 64 + nf * 16 + (lane & 15);
#pragma unroll
      for (int r = 0; r < 4; ++r) {
        int m = m0 + wm * 64 + mf * 16 + (lane >> 4) * 4 + r;
        out[(size_t)m * DIM + e] = acc[mf][nf][r];
      }
    }
}

// ---------------- Flash attention, swapped-QK^T + in-register P (T12 full) ----
// grid: (L/128, B*H). block 256 = 4 waves; each wave owns 32 query rows.
// S^T = mfma(K,Q): lane owns one q-column, 16 kv values in regs per qi.
// P->PV B-fragment rearrangement fully in-register: cvt_pk_bf16 pairs +
// permlane32_swap/permlane16_swap (no LDS round-trip, no lgkm drain).
// LDS = Ks+Vts+bias = 36KB -> 4 blocks/CU co-resident (grid 1024 = 4*256CU).
__global__ __launch_bounds__(256, 4) void attn_kernel(
    const unsigned short* __restrict__ qw, const unsigned short* __restrict__ kw,
    const unsigned short* __restrict__ vtw, const int* __restrict__ mask,
    unsigned short* __restrict__ yb) {
  __shared__ unsigned short Ks[2][64 * 64];    // [buf][kv][hd] swizzled
  __shared__ unsigned short Vts[2][64 * 64];   // [buf][hd][kv] swizzled
  __shared__ __bf16        BiasL[L_SEQ];       // 0 or -1e30 per key
  const int bh = blockIdx.y;
  const int q0 = blockIdx.x * 128;
  const int b = bh >> 4, h = bh & 15;
  const int t = threadIdx.x, wid = t >> 6, lane = t & 63;
  const int lr = lane & 15, lk = (lane >> 4) * 8, g4 = (lane >> 4) * 4;
  const int swr = (lr & 7) << 3;            // read-side element XOR
  const float KE = 0.18033688011112042f;    // (1/sqrt(64)) * log2(e)

  // stage mask row as additive bias (bf16) into LDS once
  {
    const int* mrow = mask + b * L_SEQ + t * 8;
    int4 a = *(const int4*)(mrow);
    int4 c2 = *(const int4*)(mrow + 4);
    const __bf16 BN = (__bf16)(-1.0e30f), BZ = (__bf16)(0.0f);
    bf16x8 bv;
    bv[0] = a.x ? BN : BZ;  bv[1] = a.y ? BN : BZ;
    bv[2] = a.z ? BN : BZ;  bv[3] = a.w ? BN : BZ;
    bv[4] = c2.x ? BN : BZ; bv[5] = c2.y ? BN : BZ;
    bv[6] = c2.z ? BN : BZ; bv[7] = c2.w ? BN : BZ;
    *(bf16x8*)(&BiasL[t * 8]) = bv;
  }

  // Q fragments (B-operand): rows q = q0 + wid*32 + qi*16 + lr
  bf16x8 qf[2][2];
  const size_t qbase = (size_t)bh * L_SEQ + q0 + wid * 32;
#pragma unroll
  for (int qi = 0; qi < 2; ++qi)
#pragma unroll
    for (int kh = 0; kh < 2; ++kh)
      qf[qi][kh] = __builtin_bit_cast(bf16x8,
          *(const short8*)(qw + (qbase + qi * 16 + lr) * HDIM + kh * 32 + lk));

  f32x4 o[2][4] = {};                       // O^T: d = df*16+g*4+r, q = qi*16+lr
  float mrun[2] = {-3.0e38f, -3.0e38f};
  float lrun[2] = {0.f, 0.f};

  auto stage = [&](int buf, int kt) {
#pragma unroll
    for (int i = 0; i < 2; ++i) {
      int c = i * 256 + t;
      int row = c >> 3;
      int cs = ((c & 7) ^ (row & 7)) * 8;   // inverse-swizzled source column
      gload16(kw  + ((size_t)bh * L_SEQ + kt * 64 + row) * HDIM + cs, &Ks[buf][c * 8]);
      gload16(vtw + ((size_t)bh * HDIM + row) * L_SEQ + kt * 64 + cs, &Vts[buf][c * 8]);
    }
  };

  asm volatile("s_waitcnt lgkmcnt(0)" ::: "memory");  // bias writes drained
  stage(0, 0);
  int cur = 0;

  for (int kt = 0; kt < L_SEQ / 64; ++kt) {
    const int kv0 = kt * 64;
    if (kt + 1 < L_SEQ / 64) {
      stage(cur ^ 1, kt + 1);                          // prefetch next tile
      asm volatile("s_waitcnt vmcnt(4)" ::: "memory"); // current tile landed
    } else {
      asm volatile("s_waitcnt vmcnt(0)" ::: "memory");
    }
    __builtin_amdgcn_s_barrier();
    __builtin_amdgcn_sched_barrier(0);

    // ---- QK^T: s[qi][nf] = S^T fragment, kv = nf*16+g*4+r, q = qi*16+lr ----
    const unsigned short* Kc = Ks[cur];
    f32x4 s[2][4] = {};
    __builtin_amdgcn_s_setprio(1);
#pragma unroll
    for (int nf = 0; nf < 4; ++nf) {
      bf16x8 k0 = __builtin_bit_cast(bf16x8,
          *(const short8*)(Kc + (nf * 16 + lr) * 64 + ((0 + lk) ^ swr)));
      bf16x8 k1 = __builtin_bit_cast(bf16x8,
          *(const short8*)(Kc + (nf * 16 + lr) * 64 + ((32 + lk) ^ swr)));
      s[0][nf] = __builtin_amdgcn_mfma_f32_16x16x32_bf16(k0, qf[0][0], s[0][nf], 0, 0, 0);
      s[0][nf] = __builtin_amdgcn_mfma_f32_16x16x32_bf16(k1, qf[0][1], s[0][nf], 0, 0, 0);
      s[1][nf] = __builtin_amdgcn_mfma_f32_16x16x32_bf16(k0, qf[1][0], s[1][nf], 0, 0, 0);
      s[1][nf] = __builtin_amdgcn_mfma_f32_16x16x32_bf16(k1, qf[1][1], s[1][nf], 0, 0, 0);
    }
    __builtin_amdgcn_s_setprio(0);

    // ---- mask bias (branchless) ----
#pragma unroll
    for (int nf = 0; nf < 4; ++nf) {
      bf16x4 bv4 = *(const bf16x4*)(&BiasL[kv0 + nf * 16 + g4]);
      f32x4 bb = {(float)bv4[0], (float)bv4[1], (float)bv4[2], (float)bv4[3]};
      s[0][nf] += bb;
      s[1][nf] += bb;
    }

    // ---- tile max per q-column: in-lane tree + 2 shuffles ----
    float pmax[2];
#pragma unroll
    for (int qi = 0; qi < 2; ++qi) {
      float a0 = fmaxf(fmaxf(s[qi][0][0], s[qi][0][1]), fmaxf(s[qi][0][2], s[qi][0][3]));
      float a1 = fmaxf(fmaxf(s[qi][1][0], s[qi][1][1]), fmaxf(s[qi][1][2], s[qi][1][3]));
      float a2 = fmaxf(fmaxf(s[qi][2][0], s[qi][2][1]), fmaxf(s[qi][2][2], s[qi][2][3]));
      float a3 = fmaxf(fmaxf(s[qi][3][0], s[qi][3][1]), fmaxf(s[qi][3][2], s[qi][3][3]));
      float mm = fmaxf(fmaxf(a0, a1), fmaxf(a2, a3));
      mm = fmaxf(mm, __shfl_xor(mm, 16));
      mm = fmaxf(mm, __shfl_xor(mm, 32));
      pmax[qi] = mm;
    }

    // ---- defer-max rescale (T13, THR=8 in raw-score units) ----
    bool need = (pmax[0] > mrun[0] + 8.0f) || (pmax[1] > mrun[1] + 8.0f);
    if (__any(need)) {
#pragma unroll
      for (int qi = 0; qi < 2; ++qi) {
        float mn = fmaxf(mrun[qi], pmax[qi]);
        float al = __builtin_amdgcn_exp2f((mrun[qi] - mn) * KE);
        mrun[qi] = mn;
        lrun[qi] *= al;
#pragma unroll
        for (int df = 0; df < 4; ++df) o[qi][df] *= al;
      }
    }

    // ---- exp + row-sum + in-register P->B-fragment exchange ----
    bf16x8 pb[2][2];
#pragma unroll
    for (int qi = 0; qi < 2; ++qi) {
      float mk_ = mrun[qi] * KE;
      f32x4 rs4 = {0.f, 0.f, 0.f, 0.f};
#pragma unroll
      for (int nf = 0; nf < 4; ++nf) {
#pragma unroll
        for (int r = 0; r < 4; ++r)
          s[qi][nf][r] = __builtin_amdgcn_exp2f(s[qi][nf][r] * KE - mk_);
        rs4 += s[qi][nf];
      }
      float rsum = (rs4[0] + rs4[1]) + (rs4[2] + rs4[3]);
      rsum += __shfl_xor(rsum, 16);
      rsum += __shfl_xor(rsum, 32);
      lrun[qi] += rsum;
      // pack: w[nf][rr] covers kv = nf*16 + g*4 + 2rr..+1 at this lane's q-col
      unsigned w00 = cvtpk(s[qi][0][0], s[qi][0][1]);
      unsigned w01 = cvtpk(s[qi][0][2], s[qi][0][3]);
      unsigned w10 = cvtpk(s[qi][1][0], s[qi][1][1]);
      unsigned w11 = cvtpk(s[qi][1][2], s[qi][1][3]);
      unsigned w20 = cvtpk(s[qi][2][0], s[qi][2][1]);
      unsigned w21 = cvtpk(s[qi][2][2], s[qi][2][3]);
      unsigned w30 = cvtpk(s[qi][3][0], s[qi][3][1]);
      unsigned w31 = cvtpk(s[qi][3][2], s[qi][3][3]);
      // kh=0: nf pair {0,1}; kh=1: nf pair {2,3}; per rr one swap pair
      xchg(w00, w10);   // w00 -> frag0 word0, w10 -> frag0 word2
      xchg(w01, w11);   // w01 -> frag0 word1, w11 -> frag0 word3
      xchg(w20, w30);   // frag1 words 0,2
      xchg(w21, w31);   // frag1 words 1,3
      u32x4 f0 = {w00, w01, w10, w11};
      u32x4 f1 = {w20, w21, w30, w31};
      pb[qi][0] = __builtin_bit_cast(bf16x8, f0);
      pb[qi][1] = __builtin_bit_cast(bf16x8, f1);
    }

    // ---- PV: O^T += mfma(Vt, P) ----
    const unsigned short* Vc = Vts[cur];
    __builtin_amdgcn_s_setprio(1);
#pragma unroll
    for (int df = 0; df < 4; ++df) {
      bf16x8 v0 = __builtin_bit_cast(bf16x8,
          *(const short8*)(Vc + (df * 16 + lr) * 64 + ((0 + lk) ^ swr)));
      bf16x8 v1 = __builtin_bit_cast(bf16x8,
          *(const short8*)(Vc + (df * 16 + lr) * 64 + ((32 + lk) ^ swr)));
      o[0][df] = __builtin_amdgcn_mfma_f32_16x16x32_bf16(v0, pb[0][0], o[0][df], 0, 0, 0);
      o[0][df] = __builtin_amdgcn_mfma_f32_16x16x32_bf16(v1, pb[0][1], o[0][df], 0, 0, 0);
      o[1][df] = __builtin_amdgcn_mfma_f32_16x16x32_bf16(v0, pb[1][0], o[1][df], 0, 0, 0);
      o[1][df] = __builtin_amdgcn_mfma_f32_16x16x32_bf16(v1, pb[1][1], o[1][df], 0, 0, 0);
    }
    __builtin_amdgcn_s_setprio(0);

    __builtin_amdgcn_sched_barrier(0);   // all LDS reads of buf[cur] retired
    __builtin_amdgcn_s_barrier();        // before next stage overwrites it
    cur ^= 1;
  }

  // epilogue: normalize, write y[B, L, D] bf16 (b64 stores)
#pragma unroll
  for (int qi = 0; qi < 2; ++qi) {
    float inv = 1.0f / lrun[qi];
    int q = q0 + wid * 32 + qi * 16 + lr;
#pragma unroll
    for (int df = 0; df < 4; ++df) {
      bf16x4 pk = {(__bf16)(o[qi][df][0] * inv), (__bf16)(o[qi][df][1] * inv),
                   (__bf16)(o[qi][df][2] * inv), (__bf16)(o[qi][df][3] * inv)};
      *(bf16x4*)(yb + ((size_t)b * L_SEQ + q) * DIM + h * 64 + df * 16 + g4) = pk;
    }
  }
}

// ---------------- launch ----------------
extern "C" void kernel_launch(void* const* d_in, const int* in_sizes, int n_in,
                              void* d_out, int out_size, void* d_ws, size_t ws_size,
                              hipStream_t stream) {
  const float* x     = (const float*)d_in[0];
  const int*   mask  = (const int*)d_in[1];
  const float* wqkv  = (const float*)d_in[2];
  const float* wproj = (const float*)d_in[3];
  char* ws = (char*)d_ws;
  unsigned short* xb     = (unsigned short*)(ws + 0);          // 16 MiB
  unsigned short* wqkvb  = (unsigned short*)(ws + 16777216);   // 6 MiB
  unsigned short* wprojb = (unsigned short*)(ws + 23068672);   // 2 MiB
  unsigned short* qw     = (unsigned short*)(ws + 25165824);   // 16 MiB
  unsigned short* kw     = (unsigned short*)(ws + 41943040);   // 16 MiB
  unsigned short* vtw    = (unsigned short*)(ws + 58720256);   // 16 MiB
  unsigned short* yb     = (unsigned short*)(ws + 75497472);   // 16 MiB

  cvt_bf16<<<dim3(8388608 / 2048), 256, 0, stream>>>(x, xb, 8388608);
  cvt_bf16<<<dim3(3145728 / 2048), 256, 0, stream>>>(wqkv, wqkvb, 3145728);
  cvt_bf16<<<dim3(1048576 / 2048), 256, 0, stream>>>(wproj, wprojb, 1048576);
  gemm_qkv<<<dim3(24, 64), 256, 0, stream>>>(xb, wqkvb, qw, kw, vtw);
  attn_kernel<<<dim3(16, 64), 256, 0, stream>>>(qw, kw, vtw, mask, yb);
  gemm_proj<<<dim3(8, 64), 256, 0, stream>>>(yb, wprojb, (float*)d_out);
}

// Round 5
// 184.953 us; speedup vs baseline: 2.2339x; 1.3857x over previous
//
#include <hip/hip_runtime.h>

// Problem constants
#define L_SEQ 2048
#define DIM   1024
#define NH    16
#define HDIM  64
#define KDIM  1024   // K for both GEMMs

typedef short  short8 __attribute__((ext_vector_type(8)));
typedef __bf16 bf16x8 __attribute__((ext_vector_type(8)));
typedef __bf16 bf16x4 __attribute__((ext_vector_type(4)));
typedef float  f32x4  __attribute__((ext_vector_type(4)));
typedef unsigned u32x4 __attribute__((ext_vector_type(4)));

__device__ __forceinline__ unsigned short f2bf(float f) {
  unsigned u = __builtin_bit_cast(unsigned, f);
  u += 0x7fffu + ((u >> 16) & 1u);   // RNE
  return (unsigned short)(u >> 16);
}

__device__ __forceinline__ void gload16(const void* g, void* l) {
  __builtin_amdgcn_global_load_lds(
      (const __attribute__((address_space(1))) void*)g,
      (__attribute__((address_space(3))) void*)l, 16, 0, 0);
}

// pack two f32 -> one u32 of 2 bf16 (lo = a, hi = b)
__device__ __forceinline__ unsigned cvtpk(float a, float b) {
  unsigned r;
  asm("v_cvt_pk_bf16_f32 %0, %1, %2" : "=v"(r) : "v"(a), "v"(b));
  return r;
}
// after call: a = {a0,a2,b0,b2}, b = {a1,a3,b1,b3} (16-lane chunks)
__device__ __forceinline__ void xchg(unsigned &a, unsigned &b) {
  asm("v_permlane32_swap_b32 %0, %1" : "+v"(a), "+v"(b));
  asm("v_permlane16_swap_b32 %0, %1" : "+v"(a), "+v"(b));
}

// ---------------- fp32 -> bf16 conversion ----------------
__global__ __launch_bounds__(256) void cvt_bf16(const float* __restrict__ src,
                                                unsigned short* __restrict__ dst,
                                                int n) {
  int i = (blockIdx.x * 256 + threadIdx.x) * 8;
  if (i >= n) return;
  f32x4 a = *(const f32x4*)(src + i);
  f32x4 b = *(const f32x4*)(src + i + 4);
  short8 o;
  o[0] = (short)f2bf(a[0]); o[1] = (short)f2bf(a[1]);
  o[2] = (short)f2bf(a[2]); o[3] = (short)f2bf(a[3]);
  o[4] = (short)f2bf(b[0]); o[5] = (short)f2bf(b[1]);
  o[6] = (short)f2bf(b[2]); o[7] = (short)f2bf(b[3]);
  *(short8*)(dst + i) = o;
}

// ---------------- zero-fill (graph-capture-safe memset) ----------------
__global__ __launch_bounds__(256) void zero_buf(f32x4* __restrict__ dst, int n4) {
  int i = blockIdx.x * 256 + threadIdx.x;
  if (i < n4) dst[i] = f32x4{0.f, 0.f, 0.f, 0.f};
}

// ---------------- mask prefix-scan: compacted key indices ----------------
// idx[b][l] = compacted position of key l (or -1 if PAD); lc[b] = #valid keys
__global__ __launch_bounds__(256) void mask_scan(const int* __restrict__ mask,
                                                 int* __restrict__ idx,
                                                 int* __restrict__ lc) {
  const int b = blockIdx.x, t = threadIdx.x;
  __shared__ int wsum[4];
  const int* mrow = mask + b * L_SEQ + t * 8;
  int m[8], c = 0;
#pragma unroll
  for (int i = 0; i < 8; ++i) { m[i] = mrow[i]; c += (m[i] == 0); }
  const int lane = t & 63, w = t >> 6;
  int sc = c;
#pragma unroll
  for (int d = 1; d < 64; d <<= 1) {
    int v = __shfl_up(sc, d);
    if (lane >= d) sc += v;
  }
  if (lane == 63) wsum[w] = sc;
  __syncthreads();
  int pre = sc - c;                      // exclusive within wave
  for (int i = 0; i < w; ++i) pre += wsum[i];
  int run = pre;
#pragma unroll
  for (int i = 0; i < 8; ++i) {
    idx[b * L_SEQ + t * 8 + i] = m[i] ? -1 : run;
    run += (m[i] == 0);
  }
  if (t == 255) lc[b] = run;
}

// ---------------- 128x128 NT GEMM mainloop (m97 structure) ----------------
__device__ __forceinline__ void gemm128_mainloop(
    const unsigned short* __restrict__ A, const unsigned short* __restrict__ Bt,
    int m0, int n0, unsigned short* As, unsigned short* Bs, f32x4 (&acc)[4][4]) {
  const int t = threadIdx.x;
  const int wid = t >> 6, lane = t & 63;
  const int wm = wid >> 1, wn = wid & 1;
  const int lr = lane & 15, lk = (lane >> 4) * 8;
  for (int kt = 0; kt < KDIM / 64; ++kt) {
    __syncthreads();
#pragma unroll
    for (int i = 0; i < 4; ++i) {
      int c = i * 256 + t;
      int row = c >> 3, cc = (c & 7) * 8;
      gload16(A  + (size_t)(m0 + row) * KDIM + kt * 64 + cc, As + c * 8);
      gload16(Bt + (size_t)(n0 + row) * KDIM + kt * 64 + cc, Bs + c * 8);
    }
    asm volatile("s_waitcnt vmcnt(0)" ::: "memory");
    __syncthreads();
    bf16x8 af[4][2], bfv[4][2];
#pragma unroll
    for (int mf = 0; mf < 4; ++mf)
#pragma unroll
      for (int kh = 0; kh < 2; ++kh)
        af[mf][kh] = __builtin_bit_cast(bf16x8,
            *(const short8*)(As + (wm * 64 + mf * 16 + lr) * 64 + kh * 32 + lk));
#pragma unroll
    for (int nf = 0; nf < 4; ++nf)
#pragma unroll
      for (int kh = 0; kh < 2; ++kh)
        bfv[nf][kh] = __builtin_bit_cast(bf16x8,
            *(const short8*)(Bs + (wn * 64 + nf * 16 + lr) * 64 + kh * 32 + lk));
#pragma unroll
    for (int mf = 0; mf < 4; ++mf)
#pragma unroll
      for (int nf = 0; nf < 4; ++nf)
#pragma unroll
        for (int kh = 0; kh < 2; ++kh)
          acc[mf][nf] = __builtin_amdgcn_mfma_f32_16x16x32_bf16(
              af[mf][kh], bfv[nf][kh], acc[mf][nf], 0, 0, 0);
  }
}

// ---------------- GEMM1: qkv = x @ Wqkv^T, scatter (K/V compacted) ----------
__global__ __launch_bounds__(256) void gemm_qkv(
    const unsigned short* __restrict__ xb, const unsigned short* __restrict__ wb,
    const int* __restrict__ idx,
    unsigned short* __restrict__ qw, unsigned short* __restrict__ kw,
    unsigned short* __restrict__ vtw) {
  __shared__ unsigned short As[128 * 64], Bs[128 * 64];
  f32x4 acc[4][4] = {};
  const int n0 = blockIdx.x * 128, m0 = blockIdx.y * 128;
  gemm128_mainloop(xb, wb, m0, n0, As, Bs, acc);
  const int t = threadIdx.x, wid = t >> 6, lane = t & 63;
  const int wm = wid >> 1, wn = wid & 1;
  const int sec = n0 >> 10;              // 0=Q 1=K 2=V (block-uniform)
  const int nb = n0 & 1023;
  if (sec == 0) {
#pragma unroll
    for (int mf = 0; mf < 4; ++mf)
#pragma unroll
      for (int nf = 0; nf < 4; ++nf) {
        int e = nb + wn * 64 + nf * 16 + (lane & 15);
        int h = e >> 6, hd = e & 63;
#pragma unroll
        for (int r = 0; r < 4; ++r) {
          int m = m0 + wm * 64 + mf * 16 + (lane >> 4) * 4 + r;
          int b = m >> 11, li = m & 2047;
          qw[(((size_t)(b * NH + h)) * L_SEQ + li) * HDIM + hd] =
              f2bf(acc[mf][nf][r]);
        }
      }
  } else {
#pragma unroll
    for (int mf = 0; mf < 4; ++mf)
#pragma unroll
      for (int r = 0; r < 4; ++r) {
        int m = m0 + wm * 64 + mf * 16 + (lane >> 4) * 4 + r;
        int b = m >> 11, li = m & 2047;
        int tgt = idx[b * L_SEQ + li];   // -1 = PAD: drop row
        if (tgt < 0) continue;
        size_t bb = (size_t)b * NH;
#pragma unroll
        for (int nf = 0; nf < 4; ++nf) {
          int e = nb + wn * 64 + nf * 16 + (lane & 15);
          int h = e >> 6, hd = e & 63;
          unsigned short val = f2bf(acc[mf][nf][r]);
          if (sec == 1) kw[((bb + h) * L_SEQ + tgt) * HDIM + hd] = val;
          else          vtw[((bb + h) * HDIM + hd) * L_SEQ + tgt] = val;
        }
      }
  }
}

// ---------------- GEMM2: out = y @ Wproj^T (fp32 out) ----------------
__global__ __launch_bounds__(256) void gemm_proj(
    const unsigned short* __restrict__ yb, const unsigned short* __restrict__ wb,
    float* __restrict__ out) {
  __shared__ unsigned short As[128 * 64], Bs[128 * 64];
  f32x4 acc[4][4] = {};
  const int n0 = blockIdx.x * 128, m0 = blockIdx.y * 128;
  gemm128_mainloop(yb, wb, m0, n0, As, Bs, acc);
  const int t = threadIdx.x, wid = t >> 6, lane = t & 63;
  const int wm = wid >> 1, wn = wid & 1;
#pragma unroll
  for (int mf = 0; mf < 4; ++mf)
#pragma unroll
    for (int nf = 0; nf < 4; ++nf) {
      int e = n0 + wn * 64 + nf * 16 + (lane & 15);
#pragma unroll
      for (int r = 0; r < 4; ++r) {
        int m = m0 + wm * 64 + mf * 16 + (lane >> 4) * 4 + r;
        out[(size_t)m * DIM + e] = acc[mf][nf][r];
      }
    }
}

// ---------------- Flash attention over COMPACTED keys ----------------
// grid: (L/128, B*H). block 256 = 4 waves; each wave owns 32 query rows.
// Keys/values pre-compacted to the unmasked subset (length Lc[b]): softmax
// over compacted keys == masked softmax. Only the last (partial) tile needs
// handling: s overwritten with -3e38 for kv>=Lc (NaN-proof), V tail zeroed
// globally so PV contributes 0.
__global__ __launch_bounds__(256, 4) void attn_kernel(
    const unsigned short* __restrict__ qw, const unsigned short* __restrict__ kw,
    const unsigned short* __restrict__ vtw, const int* __restrict__ lc,
    unsigned short* __restrict__ yb) {
  __shared__ unsigned short Ks[2][64 * 64];    // [buf][kv][hd] swizzled
  __shared__ unsigned short Vts[2][64 * 64];   // [buf][hd][kv] swizzled
  const int bh = blockIdx.y;
  const int q0 = blockIdx.x * 128;
  const int b = bh >> 4, h = bh & 15;
  const int t = threadIdx.x, wid = t >> 6, lane = t & 63;
  const int lr = lane & 15, lk = (lane >> 4) * 8, g4 = (lane >> 4) * 4;
  const int swr = (lr & 7) << 3;            // read-side element XOR
  const float KE = 0.18033688011112042f;    // (1/sqrt(64)) * log2(e)

  const int Lcv = lc[b];
  const int nt = (Lcv + 63) >> 6;           // >=1 (never fully padded)

  // Q fragments (B-operand): rows q = q0 + wid*32 + qi*16 + lr
  bf16x8 qf[2][2];
  const size_t qbase = (size_t)bh * L_SEQ + q0 + wid * 32;
#pragma unroll
  for (int qi = 0; qi < 2; ++qi)
#pragma unroll
    for (int kh = 0; kh < 2; ++kh)
      qf[qi][kh] = __builtin_bit_cast(bf16x8,
          *(const short8*)(qw + (qbase + qi * 16 + lr) * HDIM + kh * 32 + lk));

  f32x4 o[2][4] = {};                       // O^T: d = df*16+g*4+r, q = qi*16+lr
  float mrun[2] = {-3.0e38f, -3.0e38f};
  float lrun[2] = {0.f, 0.f};

  auto stage = [&](int buf, int kt) {
#pragma unroll
    for (int i = 0; i < 2; ++i) {
      int c = i * 256 + t;
      int row = c >> 3;
      int cs = ((c & 7) ^ (row & 7)) * 8;   // inverse-swizzled source column
      gload16(kw  + ((size_t)bh * L_SEQ + kt * 64 + row) * HDIM + cs, &Ks[buf][c * 8]);
      gload16(vtw + ((size_t)bh * HDIM + row) * L_SEQ + kt * 64 + cs, &Vts[buf][c * 8]);
    }
  };

  stage(0, 0);
  int cur = 0;

  for (int kt = 0; kt < nt; ++kt) {
    if (kt + 1 < nt) {
      stage(cur ^ 1, kt + 1);                          // prefetch next tile
      asm volatile("s_waitcnt vmcnt(4)" ::: "memory"); // current tile landed
    } else {
      asm volatile("s_waitcnt vmcnt(0)" ::: "memory");
    }
    __builtin_amdgcn_s_barrier();
    __builtin_amdgcn_sched_barrier(0);

    // ---- QK^T: s[qi][nf] = S^T fragment, kv = nf*16+g*4+r, q = qi*16+lr ----
    const unsigned short* Kc = Ks[cur];
    f32x4 s[2][4] = {};
    __builtin_amdgcn_s_setprio(1);
#pragma unroll
    for (int nf = 0; nf < 4; ++nf) {
      bf16x8 k0 = __builtin_bit_cast(bf16x8,
          *(const short8*)(Kc + (nf * 16 + lr) * 64 + ((0 + lk) ^ swr)));
      bf16x8 k1 = __builtin_bit_cast(bf16x8,
          *(const short8*)(Kc + (nf * 16 + lr) * 64 + ((32 + lk) ^ swr)));
      s[0][nf] = __builtin_amdgcn_mfma_f32_16x16x32_bf16(k0, qf[0][0], s[0][nf], 0, 0, 0);
      s[0][nf] = __builtin_amdgcn_mfma_f32_16x16x32_bf16(k1, qf[0][1], s[0][nf], 0, 0, 0);
      s[1][nf] = __builtin_amdgcn_mfma_f32_16x16x32_bf16(k0, qf[1][0], s[1][nf], 0, 0, 0);
      s[1][nf] = __builtin_amdgcn_mfma_f32_16x16x32_bf16(k1, qf[1][1], s[1][nf], 0, 0, 0);
    }
    __builtin_amdgcn_s_setprio(0);

    // ---- tail tile: overwrite out-of-range scores (kills stale/NaN K too) --
    if (kt == nt - 1) {
      int kbase = kt * 64 + g4;
#pragma unroll
      for (int nf = 0; nf < 4; ++nf)
#pragma unroll
        for (int r = 0; r < 4; ++r)
          if (kbase + nf * 16 + r >= Lcv) {
            s[0][nf][r] = -3.0e38f;
            s[1][nf][r] = -3.0e38f;
          }
    }

    // ---- tile max per q-column: in-lane tree + 2 shuffles ----
    float pmax[2];
#pragma unroll
    for (int qi = 0; qi < 2; ++qi) {
      float a0 = fmaxf(fmaxf(s[qi][0][0], s[qi][0][1]), fmaxf(s[qi][0][2], s[qi][0][3]));
      float a1 = fmaxf(fmaxf(s[qi][1][0], s[qi][1][1]), fmaxf(s[qi][1][2], s[qi][1][3]));
      float a2 = fmaxf(fmaxf(s[qi][2][0], s[qi][2][1]), fmaxf(s[qi][2][2], s[qi][2][3]));
      float a3 = fmaxf(fmaxf(s[qi][3][0], s[qi][3][1]), fmaxf(s[qi][3][2], s[qi][3][3]));
      float mm = fmaxf(fmaxf(a0, a1), fmaxf(a2, a3));
      mm = fmaxf(mm, __shfl_xor(mm, 16));
      mm = fmaxf(mm, __shfl_xor(mm, 32));
      pmax[qi] = mm;
    }

    // ---- defer-max rescale (T13, THR=8 in raw-score units) ----
    bool need = (pmax[0] > mrun[0] + 8.0f) || (pmax[1] > mrun[1] + 8.0f);
    if (__any(need)) {
#pragma unroll
      for (int qi = 0; qi < 2; ++qi) {
        float mn = fmaxf(mrun[qi], pmax[qi]);
        float al = __builtin_amdgcn_exp2f((mrun[qi] - mn) * KE);
        mrun[qi] = mn;
        lrun[qi] *= al;
#pragma unroll
        for (int df = 0; df < 4; ++df) o[qi][df] *= al;
      }
    }

    // ---- exp + row-sum + in-register P->B-fragment exchange ----
    bf16x8 pb[2][2];
#pragma unroll
    for (int qi = 0; qi < 2; ++qi) {
      float mk_ = mrun[qi] * KE;
      f32x4 rs4 = {0.f, 0.f, 0.f, 0.f};
#pragma unroll
      for (int nf = 0; nf < 4; ++nf) {
#pragma unroll
        for (int r = 0; r < 4; ++r)
          s[qi][nf][r] = __builtin_amdgcn_exp2f(s[qi][nf][r] * KE - mk_);
        rs4 += s[qi][nf];
      }
      float rsum = (rs4[0] + rs4[1]) + (rs4[2] + rs4[3]);
      rsum += __shfl_xor(rsum, 16);
      rsum += __shfl_xor(rsum, 32);
      lrun[qi] += rsum;
      unsigned w00 = cvtpk(s[qi][0][0], s[qi][0][1]);
      unsigned w01 = cvtpk(s[qi][0][2], s[qi][0][3]);
      unsigned w10 = cvtpk(s[qi][1][0], s[qi][1][1]);
      unsigned w11 = cvtpk(s[qi][1][2], s[qi][1][3]);
      unsigned w20 = cvtpk(s[qi][2][0], s[qi][2][1]);
      unsigned w21 = cvtpk(s[qi][2][2], s[qi][2][3]);
      unsigned w30 = cvtpk(s[qi][3][0], s[qi][3][1]);
      unsigned w31 = cvtpk(s[qi][3][2], s[qi][3][3]);
      xchg(w00, w10);
      xchg(w01, w11);
      xchg(w20, w30);
      xchg(w21, w31);
      u32x4 f0 = {w00, w01, w10, w11};
      u32x4 f1 = {w20, w21, w30, w31};
      pb[qi][0] = __builtin_bit_cast(bf16x8, f0);
      pb[qi][1] = __builtin_bit_cast(bf16x8, f1);
    }

    // ---- PV: O^T += mfma(Vt, P) ----
    const unsigned short* Vc = Vts[cur];
    __builtin_amdgcn_s_setprio(1);
#pragma unroll
    for (int df = 0; df < 4; ++df) {
      bf16x8 v0 = __builtin_bit_cast(bf16x8,
          *(const short8*)(Vc + (df * 16 + lr) * 64 + ((0 + lk) ^ swr)));
      bf16x8 v1 = __builtin_bit_cast(bf16x8,
          *(const short8*)(Vc + (df * 16 + lr) * 64 + ((32 + lk) ^ swr)));
      o[0][df] = __builtin_amdgcn_mfma_f32_16x16x32_bf16(v0, pb[0][0], o[0][df], 0, 0, 0);
      o[0][df] = __builtin_amdgcn_mfma_f32_16x16x32_bf16(v1, pb[0][1], o[0][df], 0, 0, 0);
      o[1][df] = __builtin_amdgcn_mfma_f32_16x16x32_bf16(v0, pb[1][0], o[1][df], 0, 0, 0);
      o[1][df] = __builtin_amdgcn_mfma_f32_16x16x32_bf16(v1, pb[1][1], o[1][df], 0, 0, 0);
    }
    __builtin_amdgcn_s_setprio(0);

    __builtin_amdgcn_sched_barrier(0);   // all LDS reads of buf[cur] retired
    __builtin_amdgcn_s_barrier();        // before next stage overwrites it
    cur ^= 1;
  }

  // epilogue: normalize, write y[B, L, D] bf16 (b64 stores)
#pragma unroll
  for (int qi = 0; qi < 2; ++qi) {
    float inv = 1.0f / lrun[qi];
    int q = q0 + wid * 32 + qi * 16 + lr;
#pragma unroll
    for (int df = 0; df < 4; ++df) {
      bf16x4 pk = {(__bf16)(o[qi][df][0] * inv), (__bf16)(o[qi][df][1] * inv),
                   (__bf16)(o[qi][df][2] * inv), (__bf16)(o[qi][df][3] * inv)};
      *(bf16x4*)(yb + ((size_t)b * L_SEQ + q) * DIM + h * 64 + df * 16 + g4) = pk;
    }
  }
}

// ---------------- launch ----------------
extern "C" void kernel_launch(void* const* d_in, const int* in_sizes, int n_in,
                              void* d_out, int out_size, void* d_ws, size_t ws_size,
                              hipStream_t stream) {
  const float* x     = (const float*)d_in[0];
  const int*   mask  = (const int*)d_in[1];
  const float* wqkv  = (const float*)d_in[2];
  const float* wproj = (const float*)d_in[3];
  char* ws = (char*)d_ws;
  unsigned short* xb     = (unsigned short*)(ws + 0);          // 16 MiB
  unsigned short* wqkvb  = (unsigned short*)(ws + 16777216);   // 6 MiB
  unsigned short* wprojb = (unsigned short*)(ws + 23068672);   // 2 MiB
  unsigned short* qw     = (unsigned short*)(ws + 25165824);   // 16 MiB
  unsigned short* kw     = (unsigned short*)(ws + 41943040);   // 16 MiB
  unsigned short* vtw    = (unsigned short*)(ws + 58720256);   // 16 MiB
  unsigned short* yb     = (unsigned short*)(ws + 75497472);   // 16 MiB
  int*            idx    = (int*)(ws + 92274688);              // 32 KiB
  int*            lcArr  = (int*)(ws + 92307456);              // 16 B

  cvt_bf16<<<dim3(8388608 / 2048), 256, 0, stream>>>(x, xb, 8388608);
  cvt_bf16<<<dim3(3145728 / 2048), 256, 0, stream>>>(wqkv, wqkvb, 3145728);
  cvt_bf16<<<dim3(1048576 / 2048), 256, 0, stream>>>(wproj, wprojb, 1048576);
  mask_scan<<<dim3(4), 256, 0, stream>>>(mask, idx, lcArr);
  zero_buf<<<dim3(4096), 256, 0, stream>>>((f32x4*)vtw, 1048576);  // V tail NaN-safe
  gemm_qkv<<<dim3(24, 64), 256, 0, stream>>>(xb, wqkvb, idx, qw, kw, vtw);
  attn_kernel<<<dim3(16, 64), 256, 0, stream>>>(qw, kw, vtw, lcArr, yb);
  gemm_proj<<<dim3(8, 64), 256, 0, stream>>>(yb, wprojb, (float*)d_out);
}